// Round 2
// baseline (2696.408 us; speedup 1.0000x reference)
//
#include <hip/hip_runtime.h>

#define NB 4
#define NT 8192
#define NC 64
#define NS 256
#define NV 256
#define NL 30

#define X_FLOATS  (NB * NT * NC)          // 2,097,152
#define SK_FLOATS (NB * NT * NS)          // 8,388,608
#define WS_NEEDED ((size_t)(2 * X_FLOATS + SK_FLOATS) * sizeof(float))  // 48 MB

// ---------------------------------------------------------------------------
__global__ void sentinel_kernel(float* __restrict__ out) {
  if (threadIdx.x == 0) out[0] = -1234.0f;
}

__global__ void zero_kernel(float* __restrict__ out) {
  if (threadIdx.x == 0) out[0] = 0.0f;
}

// ---------------------------------------------------------------------------
// Embedding lookup: x0[b,t,:] = embed[shifted_label(b,t), :]
// ---------------------------------------------------------------------------
__global__ __launch_bounds__(256) void embed_kernel(
    const int* __restrict__ wf, const float* __restrict__ embed,
    float* __restrict__ x0)
{
  const int bidx = blockIdx.x;          // 512 blocks, 64 positions each
  const int bb = bidx >> 7;             // 128 blocks per batch (8192/64)
  const int t0 = (bidx & 127) << 6;
  const int pos0 = bb * NT + t0;
  for (int e = threadIdx.x; e < 64 * 64; e += 256) {
    int p = e >> 6, c = e & 63;
    int t = t0 + p;
    int id = (t == 0) ? 128 : wf[bb * NT + t - 1];
    x0[(pos0 + p) * NC + c] = embed[id * NC + c];
  }
}

// ---------------------------------------------------------------------------
// One WaveNet layer: conv(k=2, dilation d) -> gate -> residual + skip accum
// 512 blocks x 256 threads; 64 positions per block.
// ---------------------------------------------------------------------------
__global__ __launch_bounds__(256) void layer_kernel(
    const float* __restrict__ xin, float* __restrict__ xout,
    float* __restrict__ skip,
    const float* __restrict__ cw,   // [2][64][128]
    const float* __restrict__ cb,   // [128]
    const float* __restrict__ rw,   // [64][64]
    const float* __restrict__ rb,   // [64]
    const float* __restrict__ sw,   // [64][256]
    const float* __restrict__ sb,   // [256]
    int d, int first)
{
  __shared__ float xt[64][68];    // x[t] tile      (pad 68: bank-safe, 16B rows)
  __shared__ float xdt[64][68];   // x[t-d] tile
  __shared__ float gt[64][68];    // gate tile

  const int tid = threadIdx.x;
  const int bidx = blockIdx.x;
  const int bb = bidx >> 7;
  const int t0 = (bidx & 127) << 6;
  const int pos0 = bb * NT + t0;

  // ---- stage x and shifted x ----
  for (int e = tid; e < 64 * 64; e += 256) {
    int p = e >> 6, c = e & 63;
    xt[p][c] = xin[(pos0 + p) * NC + c];
    int ts = t0 + p - d;
    xdt[p][c] = (ts >= 0) ? xin[(bb * NT + ts) * NC + c] : 0.f;
  }
  __syncthreads();

  const int wv = tid >> 6;        // wave 0..3
  const int lane = tid & 63;

  // ---- conv + gate: wave -> 16 positions, lane -> gate feature g ----
  {
    const int g = lane;
    const int p0 = wv << 4;
    float hA[16], hB[16];
#pragma unroll
    for (int p = 0; p < 16; ++p) { hA[p] = cb[g]; hB[p] = cb[g + 64]; }
    for (int kc = 0; kc < 64; kc += 8) {
      float w0a[8], w1a[8], w0b[8], w1b[8];
#pragma unroll
      for (int k = 0; k < 8; ++k) {
        w0a[k] = cw[(kc + k) * 128 + g];
        w1a[k] = cw[8192 + (kc + k) * 128 + g];
        w0b[k] = cw[(kc + k) * 128 + g + 64];
        w1b[k] = cw[8192 + (kc + k) * 128 + g + 64];
      }
#pragma unroll
      for (int p = 0; p < 16; ++p) {
        const int pp = p0 + p;
#pragma unroll
        for (int k = 0; k < 8; k += 4) {
          float4 xdv = *(const float4*)&xdt[pp][kc + k];
          float4 xv  = *(const float4*)&xt[pp][kc + k];
          hA[p] += xdv.x * w0a[k] + xdv.y * w0a[k + 1] + xdv.z * w0a[k + 2] + xdv.w * w0a[k + 3];
          hA[p] += xv.x  * w1a[k] + xv.y  * w1a[k + 1] + xv.z  * w1a[k + 2] + xv.w  * w1a[k + 3];
          hB[p] += xdv.x * w0b[k] + xdv.y * w0b[k + 1] + xdv.z * w0b[k + 2] + xdv.w * w0b[k + 3];
          hB[p] += xv.x  * w1b[k] + xv.y  * w1b[k + 1] + xv.z  * w1b[k + 2] + xv.w  * w1b[k + 3];
        }
      }
    }
#pragma unroll
    for (int p = 0; p < 16; ++p) {
      float e2 = __expf(2.f * hA[p]);
      float th = (e2 - 1.f) / (e2 + 1.f);
      float sg = 1.f / (1.f + __expf(-hB[p]));
      gt[p0 + p][g] = th * sg;
    }
  }
  __syncthreads();

  // ---- residual: wave -> 16 positions, lane -> channel c ----
  {
    const int c = lane;
    const int p0 = wv << 4;
    float wcol[64];
#pragma unroll
    for (int gg = 0; gg < 64; ++gg) wcol[gg] = rw[gg * 64 + c];
    const float rbias = rb[c];
    for (int p = 0; p < 16; ++p) {
      const int pp = p0 + p;
      float acc = xt[pp][c] + rbias;
#pragma unroll
      for (int gg = 0; gg < 64; gg += 4) {
        float4 gv = *(const float4*)&gt[pp][gg];
        acc += gv.x * wcol[gg] + gv.y * wcol[gg + 1] + gv.z * wcol[gg + 2] + gv.w * wcol[gg + 3];
      }
      xout[(pos0 + pp) * NC + c] = acc;
    }
  }

  // ---- skip: lane+wave -> skip feature s (256 total), all 64 positions ----
  {
    const int s = tid;              // wv*64 + lane
    float scol[64];
#pragma unroll
    for (int gg = 0; gg < 64; ++gg) scol[gg] = sw[gg * 256 + s];
    const float sbias = sb[s];
    for (int p = 0; p < 64; ++p) {
      const int off = (pos0 + p) * NS + s;
      float acc = (first ? 0.f : skip[off]) + sbias;
#pragma unroll
      for (int gg = 0; gg < 64; gg += 4) {
        float4 gv = *(const float4*)&gt[p][gg];
        acc += gv.x * scol[gg] + gv.y * scol[gg + 1] + gv.z * scol[gg + 2] + gv.w * scol[gg + 3];
      }
      skip[off] = acc;
    }
  }
}

// ---------------------------------------------------------------------------
// Head: relu(skip@w0+b0)@w1+b1 -> log_softmax -> masked CE sum (atomic to out)
// 2048 blocks x 256 threads; 16 positions per block.
// ---------------------------------------------------------------------------
__global__ __launch_bounds__(256) void head_kernel(
    const float* __restrict__ skip,
    const float* __restrict__ w0, const float* __restrict__ b0,
    const float* __restrict__ w1, const float* __restrict__ b1,
    const int* __restrict__ wf, const int* __restrict__ lens,
    float* __restrict__ loss)
{
  __shared__ float st[16][260];
  __shared__ float ht[16][260];
  __shared__ float lt[16][260];
  const int tid = threadIdx.x;
  const int bidx = blockIdx.x;
  const int bb = bidx >> 9;            // 512 blocks per batch (8192/16)
  const int t0 = (bidx & 511) << 4;
  const int pos0 = bb * NT + t0;

  for (int e = tid; e < 16 * 256; e += 256) {
    int p = e >> 8, s = e & 255;
    st[p][s] = skip[(pos0 + p) * NS + s];
  }
  __syncthreads();

  const int v = tid;  // output feature 0..255
  // hid0 = relu(skip @ w0 + b0)
  {
    float acc[16];
#pragma unroll
    for (int p = 0; p < 16; ++p) acc[p] = b0[v];
    for (int sc = 0; sc < 256; sc += 32) {
      float wreg[32];
#pragma unroll
      for (int ss = 0; ss < 32; ++ss) wreg[ss] = w0[(sc + ss) * 256 + v];
#pragma unroll
      for (int p = 0; p < 16; ++p) {
#pragma unroll
        for (int ss = 0; ss < 32; ss += 4) {
          float4 sv = *(const float4*)&st[p][sc + ss];
          acc[p] += sv.x * wreg[ss] + sv.y * wreg[ss + 1] + sv.z * wreg[ss + 2] + sv.w * wreg[ss + 3];
        }
      }
    }
#pragma unroll
    for (int p = 0; p < 16; ++p) ht[p][v] = fmaxf(acc[p], 0.f);
  }
  __syncthreads();
  // logits = hid0 @ w1 + b1
  {
    float acc[16];
#pragma unroll
    for (int p = 0; p < 16; ++p) acc[p] = b1[v];
    for (int sc = 0; sc < 256; sc += 32) {
      float wreg[32];
#pragma unroll
      for (int ss = 0; ss < 32; ++ss) wreg[ss] = w1[(sc + ss) * 256 + v];
#pragma unroll
      for (int p = 0; p < 16; ++p) {
#pragma unroll
        for (int ss = 0; ss < 32; ss += 4) {
          float4 sv = *(const float4*)&ht[p][sc + ss];
          acc[p] += sv.x * wreg[ss] + sv.y * wreg[ss + 1] + sv.z * wreg[ss + 2] + sv.w * wreg[ss + 3];
        }
      }
    }
#pragma unroll
    for (int p = 0; p < 16; ++p) lt[p][v] = acc[p];
  }
  __syncthreads();
  // log-softmax + CE, one wave per 4 positions
  const int wv = tid >> 6, lane = tid & 63;
  for (int pi = 0; pi < 4; ++pi) {
    const int p = (wv << 2) + pi;
    float x0v = lt[p][lane], x1v = lt[p][lane + 64];
    float x2v = lt[p][lane + 128], x3v = lt[p][lane + 192];
    float m = fmaxf(fmaxf(x0v, x1v), fmaxf(x2v, x3v));
#pragma unroll
    for (int off = 32; off > 0; off >>= 1) m = fmaxf(m, __shfl_xor(m, off));
    float se = __expf(x0v - m) + __expf(x1v - m) + __expf(x2v - m) + __expf(x3v - m);
#pragma unroll
    for (int off = 32; off > 0; off >>= 1) se += __shfl_xor(se, off);
    if (lane == 0) {
      const int t = t0 + p;
      if (t < lens[bb]) {
        int lbl = wf[bb * NT + t];
        float ce = (m + __logf(se)) - lt[p][lbl];
        atomicAdd(loss, ce);
      }
    }
  }
}

__global__ void finalize_kernel(const int* __restrict__ lens,
                                float* __restrict__ out)
{
  if (threadIdx.x == 0) {
    float den = 0.f;
    for (int b = 0; b < NB; ++b) {
      int l = lens[b];
      if (l > NT) l = NT;
      den += (float)l;
    }
    out[0] = out[0] / fmaxf(den, 1.f);
  }
}

// ---------------------------------------------------------------------------
extern "C" void kernel_launch(void* const* d_in, const int* in_sizes, int n_in,
                              void* d_out, int out_size, void* d_ws, size_t ws_size,
                              hipStream_t stream) {
  const int*   wf     = (const int*)d_in[0];
  const int*   lens   = (const int*)d_in[1];
  const float* embed  = (const float*)d_in[2];
  const float* conv_w = (const float*)d_in[3];
  const float* conv_b = (const float*)d_in[4];
  const float* res_w  = (const float*)d_in[5];
  const float* res_b  = (const float*)d_in[6];
  const float* skip_w = (const float*)d_in[7];
  const float* skip_b = (const float*)d_in[8];
  const float* w0     = (const float*)d_in[9];
  const float* b0     = (const float*)d_in[10];
  const float* w1     = (const float*)d_in[11];
  const float* b1     = (const float*)d_in[12];

  float* out = (float*)d_out;

  // Diagnostic guard: if ws is too small, emit sentinel so the failure mode
  // is distinguishable (absmax ~1239.5 => workspace too small).
  if (ws_size < WS_NEEDED) {
    sentinel_kernel<<<1, 64, 0, stream>>>(out);
    return;
  }

  float* ws   = (float*)d_ws;
  float* x0   = ws;                      // 2M floats (8 MB)
  float* x1   = ws + X_FLOATS;           // 2M floats (8 MB)
  float* skip = ws + 2 * X_FLOATS;       // 8M floats (32 MB)

  zero_kernel<<<1, 64, 0, stream>>>(out);
  embed_kernel<<<512, 256, 0, stream>>>(wf, embed, x0);

  static const int dil[NL] = {1, 2, 4, 8, 16, 32, 64, 128, 256, 512,
                              1, 2, 4, 8, 16, 32, 64, 128, 256, 512,
                              1, 2, 4, 8, 16, 32, 64, 128, 256, 512};
  const float* xin = x0;
  float* xout = x1;
  for (int i = 0; i < NL; ++i) {
    layer_kernel<<<512, 256, 0, stream>>>(
        xin, xout, skip,
        conv_w + (size_t)i * 2 * 64 * 128, conv_b + i * 128,
        res_w + i * 64 * 64, res_b + i * 64,
        skip_w + i * 64 * 256, skip_b + i * 256,
        dil[i], i == 0 ? 1 : 0);
    const float* t = xout; xout = (float*)xin; xin = t;
  }

  head_kernel<<<2048, 256, 0, stream>>>(skip, w0, b0, w1, b1, wf, lens, out);
  finalize_kernel<<<1, 64, 0, stream>>>(lens, out);
}

// Round 3
// 1373.599 us; speedup vs baseline: 1.9630x; 1.9630x over previous
//
#include <hip/hip_runtime.h>

#define NB 4
#define NT 8192
#define NC 64
#define NS 256
#define NV 256
#define NL 30

typedef __attribute__((ext_vector_type(8))) short bf16x8;
typedef __attribute__((ext_vector_type(4))) float f32x4;

#define MFMA(a, b, c) __builtin_amdgcn_mfma_f32_16x16x32_bf16(a, b, c, 0, 0, 0)

// weight arena layout (bf16 elements)
#define OFF_WCAT 0
#define OFF_RW   491520          // 30*128*128
#define OFF_SW   614400          // + 30*64*64
#define OFF_W0   1105920         // + 30*256*64
#define OFF_W1   1171456         // + 256*256
#define TOTAL_W  1236992         // + 256*256

#define X_FLOATS  (NB * NT * NC)               // 2,097,152 (8 MB fp32)
#define SKIP_ELEMS (NB * NT * NS)              // 8,388,608 (16 MB bf16)
#define WS_NEEDED ((size_t)(2 * X_FLOATS * 4) + (size_t)SKIP_ELEMS * 2 + (size_t)TOTAL_W * 2)

__device__ inline unsigned short f2bu(float f) {
  union { float f; unsigned u; } v; v.f = f;
  unsigned r = v.u + 0x7FFFu + ((v.u >> 16) & 1u);
  return (unsigned short)(r >> 16);
}
__device__ inline float b2f(unsigned short h) {
  union { unsigned u; float f; } v; v.u = ((unsigned)h) << 16; return v.f;
}

// ---------------------------------------------------------------------------
__global__ void sentinel_kernel(float* __restrict__ out) {
  if (threadIdx.x == 0) out[0] = -1234.0f;
}
__global__ void zero_kernel(float* __restrict__ out) {
  if (threadIdx.x == 0) out[0] = 0.0f;
}

// ---------------------------------------------------------------------------
// Pre-transpose + bf16-convert all weights into B-operand-friendly layouts:
//   wcatT[l][n=128][k=128] (k<64: conv tap0 chan k; k>=64: tap1 chan k-64)
//   rwT[l][n=64][k=64], swT[l][s=256][c=64], w0T[v][s], w1T[u][v]
// ---------------------------------------------------------------------------
__global__ __launch_bounds__(256) void prep_kernel(
    const float* __restrict__ cw, const float* __restrict__ rw,
    const float* __restrict__ sw, const float* __restrict__ w0,
    const float* __restrict__ w1, unsigned short* __restrict__ wt)
{
  int idx = blockIdx.x * 256 + threadIdx.x;
  if (idx >= TOTAL_W) return;
  float v;
  if (idx < OFF_RW) {
    int e = idx; int l = e >> 14; int rem = e & 16383;
    int n = rem >> 7; int k = rem & 127; int tap = k >> 6; int c = k & 63;
    v = cw[(((l * 2 + tap) << 6) + c) * 128 + n];
  } else if (idx < OFF_SW) {
    int e = idx - OFF_RW; int l = e >> 12; int rem = e & 4095;
    int n = rem >> 6; int k = rem & 63;
    v = rw[((l << 6) + k) * 64 + n];
  } else if (idx < OFF_W0) {
    int e = idx - OFF_SW; int l = e >> 14; int rem = e & 16383;
    int s = rem >> 6; int c = rem & 63;
    v = sw[((l << 6) + c) * 256 + s];
  } else if (idx < OFF_W1) {
    int e = idx - OFF_W0; int vv = e >> 8; int s = e & 255;
    v = w0[s * 256 + vv];
  } else {
    int e = idx - OFF_W1; int u = e >> 8; int vv = e & 255;
    v = w1[vv * 256 + u];
  }
  wt[idx] = f2bu(v);
}

// ---------------------------------------------------------------------------
__global__ __launch_bounds__(256) void embed_kernel(
    const int* __restrict__ wf, const float* __restrict__ embed,
    float* __restrict__ x0)
{
  const int bidx = blockIdx.x;          // 512 blocks, 64 positions each
  const int bb = bidx >> 7;
  const int t0 = (bidx & 127) << 6;
  const int pos0 = bb * NT + t0;
  for (int e = threadIdx.x; e < 64 * 64; e += 256) {
    int p = e >> 6, c = e & 63;
    int t = t0 + p;
    int id = (t == 0) ? 128 : wf[bb * NT + t - 1];
    x0[(pos0 + p) * NC + c] = embed[id * NC + c];
  }
}

// ---------------------------------------------------------------------------
// One layer, MFMA. 256 blocks x 256 threads; 128 positions/block, 32/wave.
// ---------------------------------------------------------------------------
__global__ __launch_bounds__(256) void layer_mfma(
    const float* __restrict__ xin, float* __restrict__ xout,
    unsigned short* __restrict__ skip,
    const unsigned short* __restrict__ wcatT, const float* __restrict__ cb,
    const unsigned short* __restrict__ rwT,  const float* __restrict__ rb,
    const unsigned short* __restrict__ swT,  const float* __restrict__ sb,
    int d, int first)
{
  __shared__ __align__(16) unsigned short gt[128][72];  // gate bf16, stride 144B
  const int tid = threadIdx.x;
  const int w = tid >> 6, lane = tid & 63;
  const int quad = lane >> 4, c16 = lane & 15;
  const int bidx = blockIdx.x;
  const int bb = bidx >> 6;             // 64 blocks per batch
  const int t0 = (bidx & 63) << 7;      // 128 positions
  const int r0 = w * 32;

  // ---- A-fragments of [Xd | X] (fp32 global -> bf16) ----
  bf16x8 af[2][4];
#pragma unroll
  for (int mt = 0; mt < 2; ++mt) {
    int t = t0 + r0 + mt * 16 + c16;
#pragma unroll
    for (int kk = 0; kk < 4; ++kk) {
      int ts = (kk < 2) ? (t - d) : t;
      int ch = (kk & 1) * 32 + quad * 8;
      bf16x8 a;
      if (ts >= 0) {
        const float* p = xin + ((size_t)(bb * NT + ts)) * 64 + ch;
        float4 lo = *(const float4*)p;
        float4 hi = *(const float4*)(p + 4);
        a[0] = (short)f2bu(lo.x); a[1] = (short)f2bu(lo.y);
        a[2] = (short)f2bu(lo.z); a[3] = (short)f2bu(lo.w);
        a[4] = (short)f2bu(hi.x); a[5] = (short)f2bu(hi.y);
        a[6] = (short)f2bu(hi.z); a[7] = (short)f2bu(hi.w);
      } else {
#pragma unroll
        for (int j = 0; j < 8; ++j) a[j] = 0;
      }
      af[mt][kk] = a;
    }
  }

  // ---- GEMM1: H = [Xd|X] @ Wcat + cb ----
  f32x4 acc1[2][8];
#pragma unroll
  for (int nt = 0; nt < 8; ++nt) {
    float bias = cb[nt * 16 + c16];
    f32x4 b4 = {bias, bias, bias, bias};
    acc1[0][nt] = b4; acc1[1][nt] = b4;
  }
#pragma unroll
  for (int nt = 0; nt < 8; ++nt) {
    const unsigned short* wp = wcatT + (nt * 16 + c16) * 128 + quad * 8;
#pragma unroll
    for (int kk = 0; kk < 4; ++kk) {
      bf16x8 bf = *(const bf16x8*)(wp + kk * 32);
      acc1[0][nt] = MFMA(af[0][kk], bf, acc1[0][nt]);
      acc1[1][nt] = MFMA(af[1][kk], bf, acc1[1][nt]);
    }
  }

  // ---- gate = tanh(H[:,:64]) * sigmoid(H[:,64:]) -> LDS (A layout prep) ----
#pragma unroll
  for (int mt = 0; mt < 2; ++mt)
#pragma unroll
    for (int nt = 0; nt < 4; ++nt)
#pragma unroll
      for (int r = 0; r < 4; ++r) {
        float hA = acc1[mt][nt][r], hB = acc1[mt][nt + 4][r];
        float e2 = __expf(2.f * hA);
        float th = (e2 - 1.f) / (e2 + 1.f);
        float sg = 1.f / (1.f + __expf(-hB));
        gt[r0 + mt * 16 + quad * 4 + r][nt * 16 + c16] =
            f2bu(th * sg);
      }

  // ---- gate A-fragments (wave-private rows: no barrier needed) ----
  bf16x8 gf[2][2];
#pragma unroll
  for (int mt = 0; mt < 2; ++mt)
#pragma unroll
    for (int kk = 0; kk < 2; ++kk)
      gf[mt][kk] = *(const bf16x8*)&gt[r0 + mt * 16 + c16][kk * 32 + quad * 8];

  // ---- GEMM2: xout = x + gate @ RW + rb ----
#pragma unroll
  for (int nt = 0; nt < 4; ++nt) {
    float bias = rb[nt * 16 + c16];
    f32x4 aA = {bias, bias, bias, bias}, aB = aA;
    const unsigned short* wp = rwT + (nt * 16 + c16) * 64 + quad * 8;
#pragma unroll
    for (int kk = 0; kk < 2; ++kk) {
      bf16x8 bf = *(const bf16x8*)(wp + kk * 32);
      aA = MFMA(gf[0][kk], bf, aA);
      aB = MFMA(gf[1][kk], bf, aB);
    }
#pragma unroll
    for (int mt = 0; mt < 2; ++mt)
#pragma unroll
      for (int r = 0; r < 4; ++r) {
        int t = t0 + r0 + mt * 16 + quad * 4 + r;
        size_t idx = ((size_t)(bb * NT + t)) * 64 + nt * 16 + c16;
        xout[idx] = (mt ? aB[r] : aA[r]) + xin[idx];
      }
  }

  // ---- GEMM3: skip += gate @ SW + sb (bf16 accumulator in global) ----
#pragma unroll
  for (int nt = 0; nt < 16; ++nt) {
    float bias = sb[nt * 16 + c16];
    f32x4 aA = {bias, bias, bias, bias}, aB = aA;
    const unsigned short* wp = swT + (nt * 16 + c16) * 64 + quad * 8;
#pragma unroll
    for (int kk = 0; kk < 2; ++kk) {
      bf16x8 bf = *(const bf16x8*)(wp + kk * 32);
      aA = MFMA(gf[0][kk], bf, aA);
      aB = MFMA(gf[1][kk], bf, aB);
    }
#pragma unroll
    for (int mt = 0; mt < 2; ++mt)
#pragma unroll
      for (int r = 0; r < 4; ++r) {
        int t = t0 + r0 + mt * 16 + quad * 4 + r;
        size_t idx = ((size_t)(bb * NT + t)) * 256 + nt * 16 + c16;
        float old = first ? 0.f : b2f(skip[idx]);
        skip[idx] = f2bu(old + (mt ? aB[r] : aA[r]));
      }
  }
}

// ---------------------------------------------------------------------------
// Head, MFMA. 512 blocks x 128 threads; 64 positions/block, 32/wave.
// ---------------------------------------------------------------------------
__global__ __launch_bounds__(128) void head_mfma(
    const unsigned short* __restrict__ skip,
    const unsigned short* __restrict__ w0T, const float* __restrict__ b0,
    const unsigned short* __restrict__ w1T, const float* __restrict__ b1,
    const int* __restrict__ wf, const int* __restrict__ lens,
    float* __restrict__ loss)
{
  __shared__ __align__(16) unsigned short ht[64][264];  // hid bf16, stride 528B
  const int tid = threadIdx.x;
  const int w = tid >> 6, lane = tid & 63;
  const int quad = lane >> 4, c16 = lane & 15;
  const int bidx = blockIdx.x;
  const int bb = bidx >> 7;             // 128 blocks per batch
  const int t0 = (bidx & 127) << 6;     // 64 positions
  const int r0 = w * 32;
  const int mylen = lens[bb];

  // ---- A-fragments of skip (already bf16) ----
  bf16x8 af[2][8];
#pragma unroll
  for (int mt = 0; mt < 2; ++mt) {
    int t = t0 + r0 + mt * 16 + c16;
    const unsigned short* sp = skip + ((size_t)(bb * NT + t)) * 256 + quad * 8;
#pragma unroll
    for (int kk = 0; kk < 8; ++kk)
      af[mt][kk] = *(const bf16x8*)(sp + kk * 32);
  }

  // ---- GEMM-A: hid = relu(skip @ w0 + b0) -> LDS bf16 ----
#pragma unroll
  for (int nt = 0; nt < 16; ++nt) {
    float bias = b0[nt * 16 + c16];
    f32x4 aA = {bias, bias, bias, bias}, aB = aA;
    const unsigned short* wp = w0T + (nt * 16 + c16) * 256 + quad * 8;
#pragma unroll
    for (int kk = 0; kk < 8; ++kk) {
      bf16x8 bf = *(const bf16x8*)(wp + kk * 32);
      aA = MFMA(af[0][kk], bf, aA);
      aB = MFMA(af[1][kk], bf, aB);
    }
#pragma unroll
    for (int mt = 0; mt < 2; ++mt)
#pragma unroll
      for (int r = 0; r < 4; ++r) {
        float v = fmaxf((mt ? aB[r] : aA[r]), 0.f);
        ht[r0 + mt * 16 + quad * 4 + r][nt * 16 + c16] = f2bu(v);
      }
  }

  // ---- hid A-fragments ----
  bf16x8 hf[2][8];
#pragma unroll
  for (int mt = 0; mt < 2; ++mt)
#pragma unroll
    for (int kk = 0; kk < 8; ++kk)
      hf[mt][kk] = *(const bf16x8*)&ht[r0 + mt * 16 + c16][kk * 32 + quad * 8];

  // labels for my 8 rows
  int lbl[2][4];
#pragma unroll
  for (int mt = 0; mt < 2; ++mt)
#pragma unroll
    for (int r = 0; r < 4; ++r)
      lbl[mt][r] = wf[bb * NT + t0 + r0 + mt * 16 + quad * 4 + r];

  // ---- GEMM-B with online log-softmax state ----
  float m_[2][4], s_[2][4], tg[2][4];
#pragma unroll
  for (int mt = 0; mt < 2; ++mt)
#pragma unroll
    for (int r = 0; r < 4; ++r) { m_[mt][r] = -1e30f; s_[mt][r] = 0.f; tg[mt][r] = -1e30f; }

#pragma unroll
  for (int nt = 0; nt < 16; ++nt) {
    float bias = b1[nt * 16 + c16];
    f32x4 aA = {bias, bias, bias, bias}, aB = aA;
    const unsigned short* wp = w1T + (nt * 16 + c16) * 256 + quad * 8;
#pragma unroll
    for (int kk = 0; kk < 8; ++kk) {
      bf16x8 bf = *(const bf16x8*)(wp + kk * 32);
      aA = MFMA(hf[0][kk], bf, aA);
      aB = MFMA(hf[1][kk], bf, aB);
    }
#pragma unroll
    for (int mt = 0; mt < 2; ++mt)
#pragma unroll
      for (int r = 0; r < 4; ++r) {
        float v = (mt ? aB[r] : aA[r]);
        float nm = fmaxf(m_[mt][r], v);
        s_[mt][r] = s_[mt][r] * __expf(m_[mt][r] - nm) + __expf(v - nm);
        m_[mt][r] = nm;
        if ((lbl[mt][r] >> 4) == nt && (lbl[mt][r] & 15) == c16) tg[mt][r] = v;
      }
  }

  // ---- cross-lane (within quad, 16 lanes) reduce; CE; wave-reduce; atomic ----
  float local = 0.f;
#pragma unroll
  for (int mt = 0; mt < 2; ++mt)
#pragma unroll
    for (int r = 0; r < 4; ++r) {
      float m = m_[mt][r], s = s_[mt][r], tv = tg[mt][r];
#pragma unroll
      for (int dd = 1; dd < 16; dd <<= 1) {
        float mo = __shfl_xor(m, dd);
        float so = __shfl_xor(s, dd);
        float to = __shfl_xor(tv, dd);
        float nm = fmaxf(m, mo);
        s = s * __expf(m - nm) + so * __expf(mo - nm);
        m = nm;
        tv = fmaxf(tv, to);
      }
      int t = t0 + r0 + mt * 16 + quad * 4 + r;
      if (c16 == 0 && t < mylen)
        local += (m + __logf(s)) - tv;
    }
#pragma unroll
  for (int dd = 1; dd < 64; dd <<= 1) local += __shfl_xor(local, dd);
  if (lane == 0) atomicAdd(loss, local);
}

__global__ void finalize_kernel(const int* __restrict__ lens,
                                float* __restrict__ out)
{
  if (threadIdx.x == 0) {
    float den = 0.f;
    for (int b = 0; b < NB; ++b) {
      int l = lens[b];
      if (l > NT) l = NT;
      den += (float)l;
    }
    out[0] = out[0] / fmaxf(den, 1.f);
  }
}

// ---------------------------------------------------------------------------
extern "C" void kernel_launch(void* const* d_in, const int* in_sizes, int n_in,
                              void* d_out, int out_size, void* d_ws, size_t ws_size,
                              hipStream_t stream) {
  const int*   wf     = (const int*)d_in[0];
  const int*   lens   = (const int*)d_in[1];
  const float* embed  = (const float*)d_in[2];
  const float* conv_w = (const float*)d_in[3];
  const float* conv_b = (const float*)d_in[4];
  const float* res_w  = (const float*)d_in[5];
  const float* res_b  = (const float*)d_in[6];
  const float* skip_w = (const float*)d_in[7];
  const float* skip_b = (const float*)d_in[8];
  const float* w0     = (const float*)d_in[9];
  const float* b0     = (const float*)d_in[10];
  const float* w1     = (const float*)d_in[11];
  const float* b1     = (const float*)d_in[12];

  float* out = (float*)d_out;
  if (ws_size < WS_NEEDED) {
    sentinel_kernel<<<1, 64, 0, stream>>>(out);
    return;
  }

  float* ws = (float*)d_ws;
  float* x0 = ws;                                   // 8 MB fp32
  float* x1 = ws + X_FLOATS;                        // 8 MB fp32
  unsigned short* skip = (unsigned short*)(ws + 2 * X_FLOATS);   // 16 MB bf16
  unsigned short* wt   = (unsigned short*)((char*)d_ws + 32 * 1024 * 1024);

  zero_kernel<<<1, 64, 0, stream>>>(out);
  prep_kernel<<<(TOTAL_W + 255) / 256, 256, 0, stream>>>(
      conv_w, res_w, skip_w, w0, w1, wt);
  embed_kernel<<<512, 256, 0, stream>>>(wf, embed, x0);

  static const int dil[NL] = {1, 2, 4, 8, 16, 32, 64, 128, 256, 512,
                              1, 2, 4, 8, 16, 32, 64, 128, 256, 512,
                              1, 2, 4, 8, 16, 32, 64, 128, 256, 512};
  const float* xin = x0;
  float* xout = x1;
  for (int i = 0; i < NL; ++i) {
    layer_mfma<<<256, 256, 0, stream>>>(
        xin, xout, skip,
        wt + OFF_WCAT + i * 16384, conv_b + i * 128,
        wt + OFF_RW   + i * 4096,  res_b + i * 64,
        wt + OFF_SW   + i * 16384, skip_b + i * 256,
        dil[i], i == 0 ? 1 : 0);
    const float* t = xout; xout = (float*)xin; xin = t;
  }

  head_mfma<<<512, 128, 0, stream>>>(skip, wt + OFF_W0, b0, wt + OFF_W1, b1,
                                     wf, lens, out);
  finalize_kernel<<<1, 64, 0, stream>>>(lens, out);
}

// Round 4
// 768.976 us; speedup vs baseline: 3.5065x; 1.7863x over previous
//
#include <hip/hip_runtime.h>

#define NB 4
#define NT 8192
#define NC 64
#define NS 256
#define NV 256
#define NL 30

typedef __attribute__((ext_vector_type(8))) short bf16x8;
typedef __attribute__((ext_vector_type(4))) float f32x4;
typedef unsigned short ushort_t;

#define MFMA(a, b, c) __builtin_amdgcn_mfma_f32_16x16x32_bf16(a, b, c, 0, 0, 0)

// weight arena layout (bf16 elements)
#define OFF_WCAT 0
#define SZ_WCAT  (NL * 16384)                 // swizzled [l][kk=4][n=128][j=32]
#define OFF_RW   (OFF_WCAT + SZ_WCAT)
#define SZ_RW    (NL * 4096)                  // swizzled [l][kk=2][n=64][j=32]
#define OFF_SW   (OFF_RW + SZ_RW)
#define SZ_SW    (NL * 16384)                 // [l][n=256][k=64]
#define OFF_W0   (OFF_SW + SZ_SW)             // [n=256][k=256]
#define OFF_W1   (OFF_W0 + 65536)             // [n=256][k=256]
#define TOTAL_W  (OFF_W1 + 65536)             // 1,236,992 elems (2.42 MB)

#define X_ELEMS  (NB * NT * NC)               // 2,097,152 (4 MB bf16)
#define SK_ELEMS (NB * NT * NS)               // 8,388,608 (16 MB bf16)
#define WS_NEEDED ((size_t)(2 * X_ELEMS + SK_ELEMS + TOTAL_W) * 2)

__device__ inline ushort_t f2bu(float f) {
  union { float f; unsigned u; } v; v.f = f;
  unsigned r = v.u + 0x7FFFu + ((v.u >> 16) & 1u);
  return (ushort_t)(r >> 16);
}
__device__ inline float b2f(ushort_t h) {
  union { unsigned u; float f; } v; v.u = ((unsigned)h) << 16; return v.f;
}

// ---------------------------------------------------------------------------
__global__ void sentinel_kernel(float* __restrict__ out) {
  if (threadIdx.x == 0) out[0] = -1234.0f;
}
__global__ void zero_kernel(float* __restrict__ out) {
  if (threadIdx.x == 0) out[0] = 0.0f;
}

// ---------------------------------------------------------------------------
// Weight prep: bf16-convert + transpose; conv/res additionally k-chunk
// swizzled so LDS B-fragment reads are contiguous 16B at 2-way bank aliasing.
// ---------------------------------------------------------------------------
__global__ __launch_bounds__(256) void prep_kernel(
    const float* __restrict__ cw, const float* __restrict__ rw,
    const float* __restrict__ sw, const float* __restrict__ w0,
    const float* __restrict__ w1, ushort_t* __restrict__ wt)
{
  int idx = blockIdx.x * 256 + threadIdx.x;
  if (idx >= TOTAL_W) return;
  float v;
  if (idx < OFF_RW) {
    int e = idx; int l = e >> 14; int r = e & 16383;
    int kk = r >> 12; int n = (r >> 5) & 127; int j = r & 31;
    int k = kk * 32 + j; int tap = k >> 6; int c = k & 63;
    v = cw[(((l * 2 + tap) << 6) + c) * 128 + n];
  } else if (idx < OFF_SW) {
    int e = idx - OFF_RW; int l = e >> 12; int r = e & 4095;
    int kk = r >> 11; int n = (r >> 5) & 63; int j = r & 31;
    int k = kk * 32 + j;
    v = rw[((l << 6) + k) * 64 + n];
  } else if (idx < OFF_W0) {
    int e = idx - OFF_SW; int l = e >> 14; int r = e & 16383;
    int n = r >> 6; int k = r & 63;
    v = sw[((l << 6) + k) * 256 + n];
  } else if (idx < OFF_W1) {
    int e = idx - OFF_W0; int n = e >> 8; int k = e & 255;
    v = w0[k * 256 + n];
  } else {
    int e = idx - OFF_W1; int n = e >> 8; int k = e & 255;
    v = w1[k * 256 + n];
  }
  wt[idx] = f2bu(v);
}

// ---------------------------------------------------------------------------
__global__ __launch_bounds__(256) void embed_kernel(
    const int* __restrict__ wf, const float* __restrict__ embed,
    ushort_t* __restrict__ x0)
{
  const int bidx = blockIdx.x;          // 512 blocks, 64 positions each
  const int bb = bidx >> 7;
  const int t0 = (bidx & 127) << 6;
  const int pos0 = bb * NT + t0;
  for (int e = threadIdx.x; e < 64 * 64; e += 256) {
    int p = e >> 6, c = e & 63;
    int t = t0 + p;
    int id = (t == 0) ? 128 : wf[bb * NT + t - 1];
    x0[(pos0 + p) * NC + c] = f2bu(embed[id * NC + c]);
  }
}

// ---------------------------------------------------------------------------
// One layer. 512 blocks x 512 threads (8 waves); 64 positions/block.
// Wave (mg,nh): mg = m-group (16 positions), nh = n-half.
// ---------------------------------------------------------------------------
__global__ __launch_bounds__(512) void layer_mfma(
    const ushort_t* __restrict__ xin, ushort_t* __restrict__ xout,
    ushort_t* __restrict__ skip,
    const ushort_t* __restrict__ wcat_s, const float* __restrict__ cb,
    const ushort_t* __restrict__ rw_s,   const float* __restrict__ rb,
    const ushort_t* __restrict__ swT,    const float* __restrict__ sb,
    int d, int first)
{
  __shared__ ushort_t lwc[16384];     // 32 KB swizzled conv weights
  __shared__ ushort_t lrw[4096];      //  8 KB swizzled res weights
  __shared__ ushort_t gt[64][72];     // gate tile, padded (stride 144 B)

  const int tid = threadIdx.x;
  const int w = tid >> 6, lane = tid & 63;
  const int quad = lane >> 4, c16 = lane & 15;
  const int mg = w >> 1, nh = w & 1;
  const int bb = blockIdx.x >> 7;
  const int t0 = (blockIdx.x & 127) << 6;
  const int tb = t0 + mg * 16;

  // ---- cooperative weight staging into LDS ----
  {
    bf16x8* dst = (bf16x8*)lwc;
    const bf16x8* s1 = (const bf16x8*)wcat_s;
#pragma unroll
    for (int i = 0; i < 4; ++i) dst[tid + i * 512] = s1[tid + i * 512];
    ((bf16x8*)lrw)[tid] = ((const bf16x8*)rw_s)[tid];
  }

  // ---- A-fragments of [Xd | X] (bf16, direct 16B loads) ----
  const int tA = tb + c16;
  bf16x8 af[4];
#pragma unroll
  for (int kk = 0; kk < 4; ++kk) {
    int ts = (kk < 2) ? (tA - d) : tA;
    int ch = (kk & 1) * 32 + quad * 8;
    if (ts >= 0) {
      af[kk] = *(const bf16x8*)(xin + ((size_t)(bb * NT + ts)) * 64 + ch);
    } else {
      bf16x8 z = {0, 0, 0, 0, 0, 0, 0, 0};
      af[kk] = z;
    }
  }
  __syncthreads();

  // ---- GEMM1: H = [Xd|X] @ Wcat + cb  (wave: M=16, tiles {q, q+4}) ----
  f32x4 accA[2], accB[2];
#pragma unroll
  for (int q = 0; q < 2; ++q) {
    int na = (nh * 2 + q) * 16 + c16;   // tanh column
    int nb_ = na + 64;                  // sigmoid column
    float ba = cb[na], bs = cb[nb_];
    f32x4 va = {ba, ba, ba, ba}, vb = {bs, bs, bs, bs};
#pragma unroll
    for (int kk = 0; kk < 4; ++kk) {
      bf16x8 bA = *(const bf16x8*)&lwc[kk * 4096 + na * 32 + quad * 8];
      va = MFMA(af[kk], bA, va);
      bf16x8 bB = *(const bf16x8*)&lwc[kk * 4096 + nb_ * 32 + quad * 8];
      vb = MFMA(af[kk], bB, vb);
    }
    accA[q] = va; accB[q] = vb;
  }

  // ---- gate -> LDS ----
#pragma unroll
  for (int q = 0; q < 2; ++q)
#pragma unroll
    for (int r = 0; r < 4; ++r) {
      float e2 = __expf(2.f * accA[q][r]);
      float th = (e2 - 1.f) / (e2 + 1.f);
      float sg = 1.f / (1.f + __expf(-accB[q][r]));
      gt[mg * 16 + quad * 4 + r][(nh * 2 + q) * 16 + c16] = f2bu(th * sg);
    }
  __syncthreads();

  // ---- gate A-fragments ----
  bf16x8 gf[2];
  gf[0] = *(const bf16x8*)&gt[mg * 16 + c16][quad * 8];
  gf[1] = *(const bf16x8*)&gt[mg * 16 + c16][32 + quad * 8];

  // ---- GEMM2: xout = x + gate @ RW + rb  (wave: M=16, N=32) ----
#pragma unroll
  for (int q = 0; q < 2; ++q) {
    int n = (nh * 2 + q) * 16 + c16;
    float bv = rb[n];
    f32x4 acc = {bv, bv, bv, bv};
    acc = MFMA(gf[0], *(const bf16x8*)&lrw[n * 32 + quad * 8], acc);
    acc = MFMA(gf[1], *(const bf16x8*)&lrw[2048 + n * 32 + quad * 8], acc);
#pragma unroll
    for (int r = 0; r < 4; ++r) {
      int tt = tb + quad * 4 + r;
      size_t idx = ((size_t)(bb * NT + tt)) * 64 + n;
      xout[idx] = f2bu(b2f(xin[idx]) + acc[r]);
    }
  }

  // ---- GEMM3: skip += gate @ SW + sb  (wave: M=16, N=128) ----
#pragma unroll
  for (int nt = 0; nt < 8; ++nt) {
    int n = (nh * 8 + nt) * 16 + c16;
    float bv = sb[n];
    f32x4 acc = {bv, bv, bv, bv};
    const ushort_t* wp = swT + n * 64 + quad * 8;
    acc = MFMA(gf[0], *(const bf16x8*)wp, acc);
    acc = MFMA(gf[1], *(const bf16x8*)(wp + 32), acc);
#pragma unroll
    for (int r = 0; r < 4; ++r) {
      int tt = tb + quad * 4 + r;
      size_t idx = ((size_t)(bb * NT + tt)) * 256 + n;
      float old = first ? 0.f : b2f(skip[idx]);
      skip[idx] = f2bu(old + acc[r]);
    }
  }
}

// ---------------------------------------------------------------------------
// Head. 512 blocks x 512 threads (8 waves); 64 positions/block.
// Wave (mg,nh): M=16, N=128 per GEMM; cross-wave softmax combine in LDS.
// ---------------------------------------------------------------------------
__global__ __launch_bounds__(512) void head_mfma(
    const ushort_t* __restrict__ skip,
    const ushort_t* __restrict__ w0T, const float* __restrict__ b0,
    const ushort_t* __restrict__ w1T, const float* __restrict__ b1,
    const int* __restrict__ wf, const int* __restrict__ lens,
    float* __restrict__ loss)
{
  __shared__ ushort_t ht[64][264];    // hid bf16, padded (stride 528 B)
  __shared__ float redM[2][64], redS[2][64], redT[2][64];

  const int tid = threadIdx.x;
  const int w = tid >> 6, lane = tid & 63;
  const int quad = lane >> 4, c16 = lane & 15;
  const int mg = w >> 1, nh = w & 1;
  const int bb = blockIdx.x >> 7;
  const int t0 = (blockIdx.x & 127) << 6;
  const int tb = t0 + mg * 16;

  // ---- skip A-fragments ----
  bf16x8 af[8];
  const ushort_t* sp = skip + ((size_t)(bb * NT + tb + c16)) * 256 + quad * 8;
#pragma unroll
  for (int kk = 0; kk < 8; ++kk)
    af[kk] = *(const bf16x8*)(sp + kk * 32);

  // ---- GEMM-A: hid = relu(skip @ w0 + b0) -> LDS ----
#pragma unroll
  for (int nt = 0; nt < 8; ++nt) {
    int n = (nh * 8 + nt) * 16 + c16;
    float bv = b0[n];
    f32x4 acc = {bv, bv, bv, bv};
    const ushort_t* wp = w0T + n * 256 + quad * 8;
#pragma unroll
    for (int kk = 0; kk < 8; ++kk)
      acc = MFMA(af[kk], *(const bf16x8*)(wp + kk * 32), acc);
#pragma unroll
    for (int r = 0; r < 4; ++r)
      ht[mg * 16 + quad * 4 + r][n] = f2bu(fmaxf(acc[r], 0.f));
  }
  __syncthreads();

  // ---- hid A-fragments ----
  bf16x8 hf[8];
#pragma unroll
  for (int kk = 0; kk < 8; ++kk)
    hf[kk] = *(const bf16x8*)&ht[mg * 16 + c16][kk * 32 + quad * 8];

  int lbl[4];
#pragma unroll
  for (int r = 0; r < 4; ++r)
    lbl[r] = wf[bb * NT + tb + quad * 4 + r];

  // ---- GEMM-B with online log-softmax over this wave's 128 columns ----
  float m_[4], s_[4], tg[4];
#pragma unroll
  for (int r = 0; r < 4; ++r) { m_[r] = -1e30f; s_[r] = 0.f; tg[r] = -1e30f; }

#pragma unroll
  for (int nt = 0; nt < 8; ++nt) {
    int n = (nh * 8 + nt) * 16 + c16;
    float bv = b1[n];
    f32x4 acc = {bv, bv, bv, bv};
    const ushort_t* wp = w1T + n * 256 + quad * 8;
#pragma unroll
    for (int kk = 0; kk < 8; ++kk)
      acc = MFMA(hf[kk], *(const bf16x8*)(wp + kk * 32), acc);
#pragma unroll
    for (int r = 0; r < 4; ++r) {
      float v = acc[r];
      float nm = fmaxf(m_[r], v);
      s_[r] = s_[r] * __expf(m_[r] - nm) + __expf(v - nm);
      m_[r] = nm;
      if (lbl[r] == n) tg[r] = v;
    }
  }

  // ---- reduce across the 16 c16 lanes (lane bits 0..3) ----
#pragma unroll
  for (int r = 0; r < 4; ++r) {
    float m = m_[r], s = s_[r], tv = tg[r];
#pragma unroll
    for (int dd = 1; dd < 16; dd <<= 1) {
      float mo = __shfl_xor(m, dd);
      float so = __shfl_xor(s, dd);
      float to = __shfl_xor(tv, dd);
      float nm = fmaxf(m, mo);
      s = s * __expf(m - nm) + so * __expf(mo - nm);
      m = nm;
      tv = fmaxf(tv, to);
    }
    if (c16 == 0) {
      int row = mg * 16 + quad * 4 + r;
      redM[nh][row] = m; redS[nh][row] = s; redT[nh][row] = tv;
    }
  }
  __syncthreads();

  // ---- combine halves, CE, block reduce (wave 0 only) ----
  if (tid < 64) {
    int row = tid;
    float m0 = redM[0][row], m1 = redM[1][row];
    float m = fmaxf(m0, m1);
    float s = redS[0][row] * __expf(m0 - m) + redS[1][row] * __expf(m1 - m);
    float tv = fmaxf(redT[0][row], redT[1][row]);
    float ce = 0.f;
    if (t0 + row < lens[bb]) ce = (m + __logf(s)) - tv;
#pragma unroll
    for (int dd = 1; dd < 64; dd <<= 1) ce += __shfl_xor(ce, dd);
    if (tid == 0) atomicAdd(loss, ce);
  }
}

__global__ void finalize_kernel(const int* __restrict__ lens,
                                float* __restrict__ out)
{
  if (threadIdx.x == 0) {
    float den = 0.f;
    for (int b = 0; b < NB; ++b) {
      int l = lens[b];
      if (l > NT) l = NT;
      den += (float)l;
    }
    out[0] = out[0] / fmaxf(den, 1.f);
  }
}

// ---------------------------------------------------------------------------
extern "C" void kernel_launch(void* const* d_in, const int* in_sizes, int n_in,
                              void* d_out, int out_size, void* d_ws, size_t ws_size,
                              hipStream_t stream) {
  const int*   wf     = (const int*)d_in[0];
  const int*   lens   = (const int*)d_in[1];
  const float* embed  = (const float*)d_in[2];
  const float* conv_w = (const float*)d_in[3];
  const float* conv_b = (const float*)d_in[4];
  const float* res_w  = (const float*)d_in[5];
  const float* res_b  = (const float*)d_in[6];
  const float* skip_w = (const float*)d_in[7];
  const float* skip_b = (const float*)d_in[8];
  const float* w0     = (const float*)d_in[9];
  const float* b0     = (const float*)d_in[10];
  const float* w1     = (const float*)d_in[11];
  const float* b1     = (const float*)d_in[12];

  float* out = (float*)d_out;
  if (ws_size < WS_NEEDED) {
    sentinel_kernel<<<1, 64, 0, stream>>>(out);
    return;
  }

  ushort_t* x0   = (ushort_t*)d_ws;       // 4 MB bf16
  ushort_t* x1   = x0 + X_ELEMS;          // 4 MB bf16
  ushort_t* skip = x1 + X_ELEMS;          // 16 MB bf16
  ushort_t* wt   = skip + SK_ELEMS;       // 2.42 MB bf16 weights

  zero_kernel<<<1, 64, 0, stream>>>(out);
  prep_kernel<<<(TOTAL_W + 255) / 256, 256, 0, stream>>>(
      conv_w, res_w, skip_w, w0, w1, wt);
  embed_kernel<<<512, 256, 0, stream>>>(wf, embed, x0);

  static const int dil[NL] = {1, 2, 4, 8, 16, 32, 64, 128, 256, 512,
                              1, 2, 4, 8, 16, 32, 64, 128, 256, 512,
                              1, 2, 4, 8, 16, 32, 64, 128, 256, 512};
  const ushort_t* xin = x0;
  ushort_t* xout = x1;
  for (int i = 0; i < NL; ++i) {
    layer_mfma<<<512, 512, 0, stream>>>(
        xin, xout, skip,
        wt + OFF_WCAT + i * 16384, conv_b + i * 128,
        wt + OFF_RW   + i * 4096,  res_b + i * 64,
        wt + OFF_SW   + i * 16384, skip_b + i * 256,
        dil[i], i == 0 ? 1 : 0);
    const ushort_t* t = xout; xout = (ushort_t*)xin; xin = t;
  }

  head_mfma<<<512, 512, 0, stream>>>(skip, wt + OFF_W0, b0, wt + OFF_W1, b1,
                                     wf, lens, out);
  finalize_kernel<<<1, 64, 0, stream>>>(lens, out);
}